// Round 5
// baseline (370.987 us; speedup 1.0000x reference)
//
#include <hip/hip_runtime.h>
#include <math.h>

#define BSZ 8192
#define DDIM 512
#define EMA_C 0.99
// acc is computed directly in logit scale: each side scaled by 8/||x|| so
// acc = 64*cos. 8 is an exact power of two -> scaling is lossless in fp16/fp32.
#define SC 64.0f
#define NFINAL 32

typedef _Float16 f16;
typedef _Float16 half8 __attribute__((ext_vector_type(8)));
typedef float f32x4 __attribute__((ext_vector_type(4)));

__device__ __forceinline__ void gload16(const void* g, void* l) {
    __builtin_amdgcn_global_load_lds(
        (const __attribute__((address_space(1))) void*)g,
        (__attribute__((address_space(3))) void*)l, 16, 0, 0);
}

// Normalize rows, scale by 8/||x||, split into fp16 hi + lo, store row-major.
// Also zeroes the stats region (pos/neg/Tsum/lossAcc/ticket) — ws is 0xAA-poisoned.
__global__ void prep_kernel(const float* __restrict__ f1,
                            const float* __restrict__ f2,
                            f16* __restrict__ Ah, f16* __restrict__ Al,
                            f16* __restrict__ Bh, f16* __restrict__ Bl,
                            float* __restrict__ stats) {
    if (blockIdx.y == 0 && blockIdx.x < 25) {
        int idx = blockIdx.x * 256 + threadIdx.x;
        if (idx < (3 * BSZ + 4) / 4)
            reinterpret_cast<float4*>(stats)[idx] = make_float4(0.f, 0.f, 0.f, 0.f);
    }
    const int w = threadIdx.x >> 6, l = threadIdx.x & 63;
    const int row = blockIdx.x * 4 + w;
    const float* src = (blockIdx.y == 0) ? f1 : f2;
    f16* dh = (blockIdx.y == 0) ? Ah : Bh;
    f16* dl = (blockIdx.y == 0) ? Al : Bl;
    const float4* p = reinterpret_cast<const float4*>(src + (size_t)row * DDIM);
    float4 v0 = p[l * 2], v1 = p[l * 2 + 1];
    float s = v0.x * v0.x + v0.y * v0.y + v0.z * v0.z + v0.w * v0.w +
              v1.x * v1.x + v1.y * v1.y + v1.z * v1.z + v1.w * v1.w;
#pragma unroll
    for (int off = 32; off; off >>= 1) s += __shfl_xor(s, off);
    const float g = 8.0f / sqrtf(s);
    float x[8] = {v0.x, v0.y, v0.z, v0.w, v1.x, v1.y, v1.z, v1.w};
    half8 h8, l8;
#pragma unroll
    for (int e = 0; e < 8; ++e) {
        float xs = x[e] * g;
        f16 hi = (f16)xs;
        h8[e] = hi;
        l8[e] = (f16)(xs - (float)hi);
    }
    *reinterpret_cast<half8*>(dh + (size_t)row * DDIM + l * 8) = h8;
    *reinterpret_cast<half8*>(dl + (size_t)row * DDIM + l * 8) = l8;
}

// 256x256 block tile, BK=32, 512 threads = 8 waves (2M x 4N), wave tile 128x64.
// Double-buffered LDS (2 x 64KB), ONE __syncthreads per K-step: stage(next)
// issues before compute(cur); the barrier's implicit vmcnt(0) drains loads
// that have had the whole MFMA phase (~3700 cyc) to land.  [T3 2-phase]
__launch_bounds__(512, 2)
__global__ void gemm_pass_kernel(const f16* __restrict__ Ah, const f16* __restrict__ Al,
                                 const f16* __restrict__ Bh, const f16* __restrict__ Bl,
                                 const int* __restrict__ label,
                                 float* __restrict__ pos,
                                 float* __restrict__ negv,
                                 float* __restrict__ Tsum) {
    // Per buffer (64KB): Ah[256][32], Al, Bh[256][32], Bl (f16; 64-B rows,
    // slot-swizzled: 16B slot s of row r holds k-group kg = s ^ ((r>>1)&3)).
    __shared__ __align__(16) char LDS[131072];

    const int t = threadIdx.x, w = t >> 6, l = t & 63;
    const int rowBase = blockIdx.y * 256;
    const int colBase = blockIdx.x * 256;

    // ---- staging addressing (pre-swizzled global src; LDS dest linear) ----
    // lane writes buffer byte q*1024 + l*16 -> row 16q + (l>>2), slot l&3
    //   -> kg = (l&3) ^ ((l>>3)&3)   (8q ≡ 0 mod 4 cancels)
    const int kg = (l & 3) ^ ((l >> 3) & 3);
    const int rsub = l >> 2;  // 0..15
    const int q0 = 2 * w, q1 = 2 * w + 1;  // each wave stages 2 q-tiles/matrix

    const f16* gAh0 = Ah + (size_t)(rowBase + 16 * q0 + rsub) * DDIM + kg * 8;
    const f16* gAh1 = Ah + (size_t)(rowBase + 16 * q1 + rsub) * DDIM + kg * 8;
    const f16* gAl0 = Al + (size_t)(rowBase + 16 * q0 + rsub) * DDIM + kg * 8;
    const f16* gAl1 = Al + (size_t)(rowBase + 16 * q1 + rsub) * DDIM + kg * 8;
    const f16* gBh0 = Bh + (size_t)(colBase + 16 * q0 + rsub) * DDIM + kg * 8;
    const f16* gBh1 = Bh + (size_t)(colBase + 16 * q1 + rsub) * DDIM + kg * 8;
    const f16* gBl0 = Bl + (size_t)(colBase + 16 * q0 + rsub) * DDIM + kg * 8;
    const f16* gBl1 = Bl + (size_t)(colBase + 16 * q1 + rsub) * DDIM + kg * 8;

    // LDS dest offsets within a buffer (wave-uniform; HW adds lane*16)
    const int oAh0 = 0 * 16384 + q0 * 1024, oAh1 = 0 * 16384 + q1 * 1024;
    const int oAl0 = 1 * 16384 + q0 * 1024, oAl1 = 1 * 16384 + q1 * 1024;
    const int oBh0 = 2 * 16384 + q0 * 1024, oBh1 = 2 * 16384 + q1 * 1024;
    const int oBl0 = 3 * 16384 + q0 * 1024, oBl1 = 3 * 16384 + q1 * 1024;

    // ---- fragment read addressing ----
    const int wrow = w >> 2, wcol = w & 3;           // 2 x 4 wave grid
    const int ar = l & 15;
    const int ssw = (l >> 4) ^ ((l >> 1) & 3);       // frag slot swizzle

    f32x4 acc[8][4];
#pragma unroll
    for (int rt = 0; rt < 8; ++rt)
#pragma unroll
        for (int ct = 0; ct < 4; ++ct) acc[rt][ct] = (f32x4){0.f, 0.f, 0.f, 0.f};

    // prologue: stage K-tile 0 into buffer 0
    {
        char* b = LDS;
        gload16(gAh0, b + oAh0); gload16(gAh1, b + oAh1);
        gload16(gAl0, b + oAl0); gload16(gAl1, b + oAl1);
        gload16(gBh0, b + oBh0); gload16(gBh1, b + oBh1);
        gload16(gBl0, b + oBl0); gload16(gBl1, b + oBl1);
    }
    __syncthreads();

    int cur = 0;
    for (int k0 = 0; k0 < DDIM; k0 += 32) {
        // stage next K-tile into the other buffer (overlaps with MFMA below)
        if (k0 + 32 < DDIM) {
            char* b = LDS + (cur ^ 1) * 65536;
            const int ko = k0 + 32;
            gload16(gAh0 + ko, b + oAh0); gload16(gAh1 + ko, b + oAh1);
            gload16(gAl0 + ko, b + oAl0); gload16(gAl1 + ko, b + oAl1);
            gload16(gBh0 + ko, b + oBh0); gload16(gBh1 + ko, b + oBh1);
            gload16(gBl0 + ko, b + oBl0); gload16(gBl1 + ko, b + oBl1);
        }

        // compute on buf[cur]
        const char* AhL = LDS + cur * 65536;
        const char* AlL = AhL + 16384;
        const char* BhL = AhL + 32768;
        const char* BlL = AhL + 49152;

        half8 bhf[4], blf[4];
#pragma unroll
        for (int ct = 0; ct < 4; ++ct) {
            const int off = (wcol * 64 + ct * 16 + ar) * 64 + ssw * 16;
            bhf[ct] = *reinterpret_cast<const half8*>(BhL + off);
            blf[ct] = *reinterpret_cast<const half8*>(BlL + off);
        }
#pragma unroll
        for (int rt = 0; rt < 8; ++rt) {
            const int off = (wrow * 128 + rt * 16 + ar) * 64 + ssw * 16;
            half8 ah = *reinterpret_cast<const half8*>(AhL + off);
            half8 al = *reinterpret_cast<const half8*>(AlL + off);
#pragma unroll
            for (int ct = 0; ct < 4; ++ct) {
                acc[rt][ct] = __builtin_amdgcn_mfma_f32_16x16x32_f16(ah, bhf[ct], acc[rt][ct], 0, 0, 0);
                acc[rt][ct] = __builtin_amdgcn_mfma_f32_16x16x32_f16(ah, blf[ct], acc[rt][ct], 0, 0, 0);
                acc[rt][ct] = __builtin_amdgcn_mfma_f32_16x16x32_f16(al, bhf[ct], acc[rt][ct], 0, 0, 0);
            }
        }
        __syncthreads();  // drains vmcnt(0)+lgkmcnt(0): next buffer ready, cur free
        cur ^= 1;
    }

    // ---- epilogue: clip, mask, exp, per-row sum/max ----
    // C/D: col = lane&15, row = (lane>>4)*4 + reg  [m89-verified layout]
    const int rowB2 = rowBase + wrow * 128;
    const int colB2 = colBase + wcol * 64;
    const int cl = l & 15, h = l >> 4;

    int lcs[4];
#pragma unroll
    for (int ct = 0; ct < 4; ++ct) lcs[ct] = label[colB2 + ct * 16 + cl];

    float psum[8][4], pmax[8][4];
#pragma unroll
    for (int rt = 0; rt < 8; ++rt)
#pragma unroll
        for (int reg = 0; reg < 4; ++reg) { psum[rt][reg] = 0.f; pmax[rt][reg] = 0.f; }

#pragma unroll
    for (int rt = 0; rt < 8; ++rt) {
        int lr[4];
#pragma unroll
        for (int reg = 0; reg < 4; ++reg) lr[reg] = label[rowB2 + rt * 16 + h * 4 + reg];
#pragma unroll
        for (int ct = 0; ct < 4; ++ct) {
            const int gcol = colB2 + ct * 16 + cl;
#pragma unroll
            for (int reg = 0; reg < 4; ++reg) {
                float v = acc[rt][ct][reg];
                v = fminf(fmaxf(v, -SC), SC);  // clip in logit units (+-64)
                const int grow = rowB2 + rt * 16 + h * 4 + reg;
                if (grow == gcol) {
                    pos[grow] = v;  // scaled diag; exactly one writer chip-wide
                } else {
                    if (lr[reg] == lcs[ct]) v = 0.0f;  // same-label mask
                    psum[rt][reg] += __expf(v);        // e^(64*cos)
                    pmax[rt][reg] = fmaxf(pmax[rt][reg], v);
                }
            }
        }
    }

#pragma unroll
    for (int rt = 0; rt < 8; ++rt)
#pragma unroll
        for (int reg = 0; reg < 4; ++reg) {
            float s = psum[rt][reg], mx = pmax[rt][reg];
#pragma unroll
            for (int m = 1; m <= 8; m <<= 1) {
                s += __shfl_xor(s, m);
                mx = fmaxf(mx, __shfl_xor(mx, m));
            }
            if (cl == 0) {
                const int grow = rowB2 + rt * 16 + h * 4 + reg;
                atomicAdd(&Tsum[grow], s);
                // values >= 0 -> int compare == float compare; init bits 0.0f
                atomicMax(reinterpret_cast<int*>(&negv[grow]), __float_as_int(mx));
            }
        }
}

// 32 blocks x 256 threads: each thread owns exactly one row. Every block
// redundantly computes the (bit-identical) m-sum; per-row loss in double;
// block partial -> f64 atomicAdd; last block (ticket) writes out.
__global__ void final_kernel(const float* __restrict__ pos,
                             const float* __restrict__ negv,
                             const float* __restrict__ Tsum,
                             double* __restrict__ lossAcc,
                             int* __restrict__ ticket,
                             float* __restrict__ out) {
    __shared__ double sd[256];
    const int t = threadIdx.x;

    // ---- mLogit = SC*m = EMA * sum(pos-neg)/B ----
    double s = 0.0;
    for (int i = t; i < BSZ; i += 256) s += (double)pos[i] - (double)negv[i];
    sd[t] = s;
    __syncthreads();
    for (int off = 128; off; off >>= 1) {
        if (t < off) sd[t] += sd[t + off];
        __syncthreads();
    }
    const double mLogit = EMA_C * sd[0] / BSZ;
    __syncthreads();

    // ---- one row per thread: loss = log(T + exp(d)) - d, stable ----
    const int row = blockIdx.x * 256 + t;  // NFINAL*256 == BSZ
    double d  = (double)pos[row] - mLogit;
    double lt = log((double)Tsum[row]);
    double l;
    if (d >= lt) l = log1p(exp(lt - d));
    else         l = (lt - d) + log1p(exp(d - lt));
    sd[t] = l;
    __syncthreads();
    for (int off = 128; off; off >>= 1) {
        if (t < off) sd[t] += sd[t + off];
        __syncthreads();
    }
    if (t == 0) {
        atomicAdd(lossAcc, sd[0]);
        __threadfence();
        int done = atomicAdd(ticket, 1);
        if (done == NFINAL - 1) {
            double total = atomicAdd(lossAcc, 0.0);  // RMW read: coherent total
            out[0] = (float)(total / BSZ);
        }
    }
}

extern "C" void kernel_launch(void* const* d_in, const int* in_sizes, int n_in,
                              void* d_out, int out_size, void* d_ws, size_t ws_size,
                              hipStream_t stream) {
    const float* f1    = (const float*)d_in[0];
    const float* f2    = (const float*)d_in[1];
    const int*   label = (const int*)d_in[2];
    float* out = (float*)d_out;

    // ws layout: pos[B], neg[B], Tsum[B] (f32), lossAcc (f64), ticket (i32),
    // pad to 16B, then Ah/Al/Bh/Bl fp16 matrices.
    float* stats = (float*)d_ws;
    float* pos   = stats;
    float* neg   = stats + BSZ;
    float* Tsum  = stats + 2 * BSZ;
    double* lossAcc = (double*)(stats + 3 * BSZ);       // byte 98304, 8-aligned
    int* ticket  = (int*)(stats + 3 * BSZ + 2);
    f16* Ah = (f16*)((char*)d_ws + 3 * BSZ * sizeof(float) + 16);
    f16* Al = Ah + (size_t)BSZ * DDIM;
    f16* Bh = Al + (size_t)BSZ * DDIM;
    f16* Bl = Bh + (size_t)BSZ * DDIM;

    prep_kernel<<<dim3(BSZ / 4, 2), dim3(256), 0, stream>>>(f1, f2, Ah, Al, Bh, Bl, stats);

    gemm_pass_kernel<<<dim3(BSZ / 256, BSZ / 256), dim3(512), 0, stream>>>(
        Ah, Al, Bh, Bl, label, pos, neg, Tsum);

    final_kernel<<<dim3(NFINAL), dim3(256), 0, stream>>>(pos, neg, Tsum, lossAcc, ticket, out);
}